// Round 2
// baseline (1187.732 us; speedup 1.0000x reference)
//
#include <hip/hip_runtime.h>

#define TT 512
#define NB 64
#define HH 128
#define G4 512
#define HDIM 256

typedef __bf16 bf16x8 __attribute__((ext_vector_type(8)));
typedef float f32x4 __attribute__((ext_vector_type(4)));
typedef unsigned int u32x4 __attribute__((ext_vector_type(4)));
typedef unsigned int u32x2 __attribute__((ext_vector_type(2)));

union FragU { u32x4 u4; bf16x8 bf; unsigned short us[8]; };
union XPU { u32x2 v; unsigned short us[4]; };

#define SC_SIG  -1.442695041f   // fold: sigma(x) = rcp(1 + exp2(-log2e * x))
#define SC_TANH -2.885390082f   // fold: tanh(x)  = 2*rcp(1 + exp2(-2log2e * x)) - 1

__device__ __forceinline__ unsigned short f2bf(float f){
  unsigned u = __builtin_bit_cast(unsigned, f);
  return (unsigned short)((u + 0x7FFFu + ((u>>16)&1u)) >> 16);
}
__device__ __forceinline__ float bf2f(unsigned short h){
  unsigned u = ((unsigned)h) << 16;
  return __builtin_bit_cast(float, u);
}
// y is pre-scaled by SC_SIG (or SC_TANH): returns sigma
__device__ __forceinline__ float rsig(float y){
  return __builtin_amdgcn_rcpf(1.0f + __builtin_amdgcn_exp2f(y));
}

// ---------------- merged prep: biases + both Bp weight repacks ----------------

__global__ __launch_bounds__(256) void k_prep(
    const float* __restrict__ bi0, const float* __restrict__ bh0,
    const float* __restrict__ bi1, const float* __restrict__ bh1,
    const float* __restrict__ w_ih0, const float* __restrict__ w_ih1,
    float* __restrict__ bias0, float* __restrict__ bias1,
    unsigned short* __restrict__ Bp0, unsigned short* __restrict__ Bp1)
{
  int id = blockIdx.x*256 + threadIdx.x;
  if (id < 2048){
    int n = id & 511;
    float s = ((n >> 7) == 2) ? SC_TANH : SC_SIG;
    if (id < 1024) bias0[id] = (bi0[id] + bh0[id]) * s;
    else { int k = id - 1024; bias1[k] = (bi1[k] + bh1[k]) * s; }
    return;
  }
  id -= 2048;
  if (id < 320*1024){
    int k = id >> 10, c = id & 1023;
    int dir = c >> 9, n = c & 511;
    float s = ((n >> 7) == 2) ? SC_TANH : SC_SIG;
    float v = (k < 300) ? w_ih0[((size_t)(dir*512 + n))*300 + k] * s : 0.f;
    Bp0[(((size_t)(k>>3))*1024 + c)*8 + (k&7)] = f2bf(v);
    return;
  }
  id -= 320*1024;
  if (id < 256*1024){
    int k = id >> 10, c = id & 1023;
    int dir = c >> 9, n = c & 511;
    float s = ((n >> 7) == 2) ? SC_TANH : SC_SIG;
    float v = w_ih1[((size_t)(dir*512 + n))*256 + k] * s;
    Bp1[(((size_t)(k>>3))*1024 + c)*8 + (k&7)] = f2bf(v);
  }
}

// x_emb[row][c] bf16, row = t*64+b, padded to 320 cols
__global__ __launch_bounds__(320) void k_embed(
    const int* __restrict__ word, const float* __restrict__ emb,
    unsigned short* __restrict__ xe)
{
  int row = blockIdx.x;       // 0..32767
  int c = threadIdx.x;        // 0..319
  int t = row >> 6, b = row & 63;
  int wd = word[b*TT + t];
  float v = (c < 300) ? emb[(size_t)wd*300 + c] : 0.f;
  xe[(size_t)row*320 + c] = f2bf(v);
}

// ---------------- input GEMM: xp = A(32768 x K) * Bp(K x 1024) + bias ----------------
// output layout: xp[t][b64][dir][u128][g4] bf16 = row*1024 + dir*512 + u*4 + g
// (row-local stride-8B scatter; matches scan's per-lane 8B gate quads)

__global__ __launch_bounds__(256) void k_gemm(
    const unsigned short* __restrict__ A,   // [32768][lda] bf16
    const unsigned short* __restrict__ Bp,  // [K/8][1024][8] bf16
    const float* __restrict__ bias,         // [1024]
    unsigned short* __restrict__ xp,
    const int lda, const int KB)
{
  const int tid = threadIdx.x;
  const int l = tid & 63, w = tid >> 6;
  const int quad = l >> 4, lo = l & 15;
  const int wm = w >> 1, wn = w & 1;
  const int M0 = blockIdx.x * 128;
  const int N0 = blockIdx.y * 128;

  __shared__ __align__(16) unsigned short Asl[4*128*8];  // [q][m][8]
  __shared__ __align__(16) unsigned short Bsl[4*128*8];  // [q][n][8]

  f32x4 acc[4][4] = {};

  for (int kb=0; kb<KB; ++kb){
    const int k0 = kb*32;
    u32x4 va[2], vb[2];
    #pragma unroll
    for (int hh=0; hh<2; ++hh){
      const int cch = tid + hh*256;
      const int q = cch >> 7, mm = cch & 127;
      va[hh] = *(const u32x4*)(A + (size_t)(M0+mm)*lda + k0 + q*8);
      vb[hh] = *(const u32x4*)(Bp + (((size_t)((k0>>3)+q))*1024 + N0 + mm)*8);
    }
    __syncthreads();   // WAR vs previous iteration's frag reads
    #pragma unroll
    for (int hh=0; hh<2; ++hh){
      const int cch = tid + hh*256;
      *(u32x4*)&Asl[cch*8] = va[hh];
      *(u32x4*)&Bsl[cch*8] = vb[hh];
    }
    __syncthreads();

    FragU af[4], bfg[4];
    #pragma unroll
    for (int mt=0; mt<4; ++mt)
      af[mt].u4 = *(const u32x4*)&Asl[((quad<<7) + wm*64 + mt*16 + lo)*8];
    #pragma unroll
    for (int nt=0; nt<4; ++nt)
      bfg[nt].u4 = *(const u32x4*)&Bsl[((quad<<7) + wn*64 + nt*16 + lo)*8];
    #pragma unroll
    for (int mt=0; mt<4; ++mt)
      #pragma unroll
      for (int nt=0; nt<4; ++nt)
        acc[mt][nt] = __builtin_amdgcn_mfma_f32_16x16x32_bf16(af[mt].bf, bfg[nt].bf, acc[mt][nt], 0, 0, 0);
  }

  #pragma unroll
  for (int mt=0; mt<4; ++mt){
    #pragma unroll
    for (int nt=0; nt<4; ++nt){
      const int col = N0 + wn*64 + nt*16 + lo;
      const int dir = col >> 9, n = col & 511;
      const int g = n >> 7, u = n & 127;
      const float bv = bias[col];
      #pragma unroll
      for (int r=0; r<4; ++r){
        const int row = M0 + wm*64 + mt*16 + quad*4 + r;
        const size_t o = (size_t)row*1024 + dir*512 + u*4 + g;
        xp[o] = f2bf(acc[mt][nt][r] + bv);
      }
    }
  }
}

// ---------------- BiLSTM scan ----------------
// LATENCY-BOUND recurrence: with one chain per WG, each step is a ~1190cy
// serial chain (barrier -> ds_read h -> 4-deep MFMA chain -> transcendental
// epilogue -> ds_write -> lgkm -> barrier) with MFMA issue only ~126cy.
// Fix: 32 WGs, each interleaving TWO independent chains (two batch-pairs,
// SAME dir so both share the 128-VGPR weight frags). Chain B's MFMA issue
// hides chain A's dep-chain + LDS latency; A's epilogue VALU overlaps B's
// MFMA issue (separate pipes). One barrier covers both. Fixed per-step
// latency amortizes over 2 logical steps.
// Replicated-A trick, BATCH-MAJOR: A[m][k] = h[m>>3][k]; every lane holds
// both batches' gates; lane selects its (batch=quad>>1, half=quad&1)
// instance with 4 cndmask. af reads are 8-lane same-address broadcasts
// (conflict-free). hbuf = 2 rows per chain. Depth-4 per-phase prefetch
// ring (per-step global traffic measured faster than ob-batched, R1).

__global__ __launch_bounds__(256, 1) void k_scan(
    const float* __restrict__ w_hh,          // [2][512][128]
    const unsigned short* __restrict__ xp,   // [t][64][2][128][4] bf16
    unsigned short* __restrict__ xout)       // [t][64][256] bf16
{
  const int bid = blockIdx.x;           // 0..31
  const int dir = bid >> 4, pg = bid & 15;
  const int tid = threadIdx.x;          // 0..255
  const int l = tid & 63, w = tid >> 6;
  const int quad = l >> 4, lo = l & 15;
  const int qb = quad >> 1;             // owned batch (0/1), batch-major
  const int qh = quad & 1;              // owned unit-half (0/1)
  const int uu = w*32 + qh*16 + lo;     // owned unit [0,128)
  const int bA = pg*4 + qb;             // chain A global batch
  const int bB = pg*4 + 2 + qb;         // chain B global batch

  // static weights as B-frags: tile nt: gate g=nt>>1, units w*32+(nt&1)*16+lo
  FragU bw[8][4];
  {
    const float* wb = w_hh + (size_t)dir*G4*HH;
    #pragma unroll
    for (int nt=0; nt<8; ++nt){
      const int g = nt >> 1;
      const float s = (g == 2) ? SC_TANH : SC_SIG;
      const int grow = g*HH + w*32 + (nt&1)*16 + lo;
      #pragma unroll
      for (int kq=0; kq<4; ++kq){
        const float* p = wb + (size_t)grow*HH + kq*32 + quad*8;
        #pragma unroll
        for (int j=0; j<8; ++j) bw[nt][kq].us[j] = f2bf(p[j] * s);
      }
    }
  }

  __shared__ __align__(16) unsigned short hbuf[2][2][2][160]; // [chain][buf][batch][k]
  for (int i = tid; i < 2*2*2*160; i += 256) ((unsigned short*)hbuf)[i] = 0;
  __syncthreads();

  float cA = 0.f, cB = 0.f;
  const int t0 = dir ? (TT-1) : 0;
  const int dt = dir ? -1 : 1;
  const unsigned short* xpA = xp + (size_t)bA*1024 + dir*512 + uu*4;
  const unsigned short* xpB = xp + (size_t)bB*1024 + dir*512 + uu*4;
  unsigned short* xoA = xout + (size_t)bA*HDIM + dir*HH + uu;
  unsigned short* xoB = xout + (size_t)bB*HDIM + dir*HH + uu;

  // depth-4 register prefetch of xp (8 B/lane/chain, dwordx2); step stride 65536
  u32x2 pfA[4], pfB[4];
  #pragma unroll
  for (int k=0; k<4; ++k){
    pfA[k] = *(const u32x2*)(xpA + (size_t)(t0 + dt*k)*65536);
    pfB[k] = *(const u32x2*)(xpB + (size_t)(t0 + dt*k)*65536);
  }

  const f32x4 zero4 = {0.f, 0.f, 0.f, 0.f};

  for (int ob=0; ob<TT/4; ++ob){
    #pragma unroll
    for (int ph=0; ph<4; ++ph){
      const int it = ob*4 + ph;
      const int t = t0 + dt*it;
      const int rb = ph & 1;          // read h buffer (starts at 0)
      const int wb2 = rb ^ 1;         // write h buffer

      // A-frags for both chains (broadcast reads, issued together)
      FragU afA[4], afB[4];
      #pragma unroll
      for (int kq=0; kq<4; ++kq)
        afA[kq].u4 = *(const u32x4*)&hbuf[0][rb][lo >> 3][kq*32 + quad*8];
      #pragma unroll
      for (int kq=0; kq<4; ++kq)
        afB[kq].u4 = *(const u32x4*)&hbuf[1][rb][lo >> 3][kq*32 + quad*8];

      // interleaved MFMA issue: A-stage then B-stage per kq; B's 8 MFMAs
      // cover A's accumulate-dependency latency and vice versa
      f32x4 accA[8], accB[8];
      #pragma unroll
      for (int nt=0; nt<8; ++nt)
        accA[nt] = __builtin_amdgcn_mfma_f32_16x16x32_bf16(afA[0].bf, bw[nt][0].bf, zero4, 0, 0, 0);
      #pragma unroll
      for (int nt=0; nt<8; ++nt)
        accB[nt] = __builtin_amdgcn_mfma_f32_16x16x32_bf16(afB[0].bf, bw[nt][0].bf, zero4, 0, 0, 0);
      #pragma unroll
      for (int kq=1; kq<4; ++kq){
        #pragma unroll
        for (int nt=0; nt<8; ++nt)
          accA[nt] = __builtin_amdgcn_mfma_f32_16x16x32_bf16(afA[kq].bf, bw[nt][kq].bf, accA[nt], 0, 0, 0);
        #pragma unroll
        for (int nt=0; nt<8; ++nt)
          accB[nt] = __builtin_amdgcn_mfma_f32_16x16x32_bf16(afB[kq].bf, bw[nt][kq].bf, accB[nt], 0, 0, 0);
      }

      // consume this phase's xp, then reload it for step it+4
      XPU xuA; xuA.v = pfA[ph];
      XPU xuB; xuB.v = pfB[ph];
      {
        const int itp = (it+4 < TT) ? (it+4) : (TT-1);
        pfA[ph] = *(const u32x2*)(xpA + (size_t)(t0 + dt*itp)*65536);
        pfB[ph] = *(const u32x2*)(xpB + (size_t)(t0 + dt*itp)*65536);
      }

      // chain A epilogue (VALU overlaps chain B's MFMA tail)
      {
        float gv[4];
        #pragma unroll
        for (int g=0; g<4; ++g)
          gv[g] = (qh ? accA[g*2+1][0] : accA[g*2][0]) + bf2f(xuA.us[g]);
        float si = rsig(gv[0]), sf = rsig(gv[1]);
        float tg = __builtin_fmaf(2.0f, rsig(gv[2]), -1.0f);
        float so = rsig(gv[3]);
        cA = __builtin_fmaf(sf, cA, si*tg);
        float h = so * __builtin_fmaf(2.0f, rsig(SC_TANH*cA), -1.0f);
        unsigned short hb = f2bf(h);
        hbuf[0][wb2][qb][uu] = hb;
        xoA[(size_t)t*NB*HDIM] = hb;
      }
      // chain B epilogue
      {
        float gv[4];
        #pragma unroll
        for (int g=0; g<4; ++g)
          gv[g] = (qh ? accB[g*2+1][0] : accB[g*2][0]) + bf2f(xuB.us[g]);
        float si = rsig(gv[0]), sf = rsig(gv[1]);
        float tg = __builtin_fmaf(2.0f, rsig(gv[2]), -1.0f);
        float so = rsig(gv[3]);
        cB = __builtin_fmaf(sf, cB, si*tg);
        float h = so * __builtin_fmaf(2.0f, rsig(SC_TANH*cB), -1.0f);
        unsigned short hb = f2bf(h);
        hbuf[1][wb2][qb][uu] = hb;
        xoB[(size_t)t*NB*HDIM] = hb;
      }

      // raw barrier: wait LDS only — vmem (prefetch/stores) stays in flight
      asm volatile("s_waitcnt lgkmcnt(0)\n\ts_barrier" ::: "memory");
    }
  }
}

// ---------------- emission GEMM: em[b][t][l] = x2 row . w_out[l] + b_out[l] ----------------

__global__ __launch_bounds__(256) void k_em(
    const unsigned short* __restrict__ x2,  // [32768][256] bf16
    const float* __restrict__ w_out,        // [9][256]
    const float* __restrict__ b_out,        // [9]
    float* __restrict__ em)                 // [64][512][9]
{
  const int tid = threadIdx.x;
  const int l = tid & 63, w = tid >> 6;
  const int quad = l >> 4, lo = l & 15;
  const int M0 = blockIdx.x*128 + w*32;

  FragU bf[8];
  #pragma unroll
  for (int kq=0; kq<8; ++kq){
    #pragma unroll
    for (int j=0; j<8; ++j){
      float v = (lo < 9) ? w_out[lo*HDIM + kq*32 + quad*8 + j] : 0.f;
      bf[kq].us[j] = f2bf(v);
    }
  }

  f32x4 acc[2] = {};
  #pragma unroll
  for (int kq=0; kq<8; ++kq){
    FragU a0, a1;
    a0.u4 = *(const u32x4*)(x2 + ((size_t)(M0 + lo))*HDIM + kq*32 + quad*8);
    a1.u4 = *(const u32x4*)(x2 + ((size_t)(M0 + 16 + lo))*HDIM + kq*32 + quad*8);
    acc[0] = __builtin_amdgcn_mfma_f32_16x16x32_bf16(a0.bf, bf[kq].bf, acc[0], 0, 0, 0);
    acc[1] = __builtin_amdgcn_mfma_f32_16x16x32_bf16(a1.bf, bf[kq].bf, acc[1], 0, 0, 0);
  }

  if (lo < 9){
    const float bo = b_out[lo];
    #pragma unroll
    for (int mt=0; mt<2; ++mt){
      #pragma unroll
      for (int r=0; r<4; ++r){
        const int row = M0 + mt*16 + quad*4 + r;
        const int t = row >> 6, b = row & 63;
        em[((size_t)b*TT + t)*9 + lo] = acc[mt][r] + bo;
      }
    }
  }
}

// ---------------- CRF: fused build + radix-8 LSE-matmul reduction ----------------

__global__ __launch_bounds__(128) void k_crf_r1f(
    const int* __restrict__ word, const float* __restrict__ em,
    const float* __restrict__ start_t, const float* __restrict__ trans,
    float* __restrict__ dst)                // [64][64][81]
{
  const int bid = blockIdx.x;       // 64*64
  const int b = bid >> 6, g = bid & 63;
  const int tid = threadIdx.x;
  const int t0 = g*8;
  __shared__ float R[2][81];
  __shared__ float emsh[8][9];
  __shared__ int wsh[8];
  if (tid < 72){
    int s = tid/9, j = tid - (tid/9)*9;
    emsh[s][j] = em[((size_t)b*TT + t0+s)*9 + j];
  }
  if (tid < 8) wsh[tid] = word[b*TT + t0 + tid];
  __syncthreads();
  int i=0, j=0; float tr[9];
  if (tid < 81){
    i = tid/9; j = tid - i*9;
    #pragma unroll
    for (int k=0;k<9;++k) tr[k] = trans[k*9+j];   // trans[i][j] = tr[i]
    float v;
    if (t0 == 0) v = start_t[j] + emsh[0][j];
    else if (wsh[0] > 0) v = tr[i] + emsh[0][j];
    else v = (i==j) ? 0.f : -1e30f;
    R[0][tid] = v;
  }
  int cur = 0;
  for (int s=1; s<8; ++s){
    __syncthreads();
    if (tid < 81){
      if (wsh[s] > 0){
        float a[9], mx = -3.0e38f;
        #pragma unroll
        for (int k=0;k<9;++k){ a[k] = R[cur][i*9+k] + tr[k]; mx = fmaxf(mx, a[k]); }
        float sm = 0.f;
        #pragma unroll
        for (int k=0;k<9;++k) sm += __expf(a[k]-mx);
        R[cur^1][tid] = mx + __logf(sm) + emsh[s][j];
      } else {
        R[cur^1][tid] = R[cur][tid];
      }
    }
    cur ^= 1;
  }
  __syncthreads();
  if (tid < 81) dst[((size_t)bid)*81 + tid] = R[cur][tid];
}

// dst = radix-8 LSE-matmul reduction of src groups (order-preserving)
__global__ __launch_bounds__(128) void k_crf_reduce(
    const float* __restrict__ src, float* __restrict__ dst, const int nm)
{
  const int bid = blockIdx.x;
  const int ng = nm >> 3;
  const int b = bid / ng, g = bid - b*ng;
  const int tid = threadIdx.x;
  __shared__ float R[2][81];
  const float* base = src + ((size_t)b*nm + g*8)*81;
  if (tid < 81) R[0][tid] = base[tid];
  int cur = 0;
  for (int s=1; s<8; ++s){
    __syncthreads();
    if (tid < 81){
      int i = tid/9, j = tid - (tid/9)*9;
      const float* M = base + (size_t)s*81;
      float a[9], mx = -3.0e38f;
      #pragma unroll
      for (int k=0;k<9;++k){ a[k] = R[cur][i*9+k] + M[k*9+j]; mx = fmaxf(mx, a[k]); }
      float sm = 0.f;
      #pragma unroll
      for (int k=0;k<9;++k) sm += __expf(a[k]-mx);
      R[cur^1][tid] = mx + __logf(sm);
    }
    cur ^= 1;
  }
  __syncthreads();
  if (tid < 81) dst[((size_t)b*ng + g)*81 + tid] = R[cur][tid];
}

__global__ __launch_bounds__(256) void k_crf_num(
    const int* __restrict__ word, const int* __restrict__ label,
    const float* __restrict__ em, const float* __restrict__ start_t,
    const float* __restrict__ end_t, const float* __restrict__ trans,
    float* __restrict__ numv)
{
  const int b = blockIdx.x, tid = threadIdx.x;
  __shared__ float sred[256];
  __shared__ int ssend;
  int ms = 0;
  for (int t=tid; t<TT; t+=256) ms += (word[b*TT+t] > 0) ? 1 : 0;
  sred[tid] = (float)ms;
  __syncthreads();
  for (int st=128; st>0; st>>=1){ if (tid<st) sred[tid] += sred[tid+st]; __syncthreads(); }
  if (tid==0) ssend = (int)sred[0] - 1;
  __syncthreads();
  const int send = ssend;
  float part = 0.f;
  for (int t=tid; t<TT; t+=256){
    int tag = label[b*TT+t];
    float es = em[((size_t)b*TT+t)*9 + tag];
    if (t == 0) part += start_t[tag] + es;
    else if (word[b*TT+t] > 0) part += trans[label[b*TT+t-1]*9 + tag] + es;
    if (t == send) part += end_t[tag];
  }
  __syncthreads();
  sred[tid] = part;
  __syncthreads();
  for (int st=128; st>0; st>>=1){ if (tid<st) sred[tid] += sred[tid+st]; __syncthreads(); }
  if (tid==0) numv[b] = sred[0];
}

__global__ __launch_bounds__(64) void k_final(
    const float* __restrict__ numv, const float* __restrict__ G3,
    const float* __restrict__ end_t, float* __restrict__ out)
{
  const int b = threadIdx.x;  // 0..63
  float a[9], mx = -3.0e38f;
  #pragma unroll
  for (int j=0;j<9;++j){ a[j] = G3[b*81 + j] + end_t[j]; mx = fmaxf(mx, a[j]); }
  float sm = 0.f;
  #pragma unroll
  for (int j=0;j<9;++j) sm += __expf(a[j]-mx);
  float denom = mx + __logf(sm);
  float v = numv[b] - denom;
  #pragma unroll
  for (int off=32; off>0; off>>=1) v += __shfl_down(v, off, 64);
  if (b == 0) out[0] = -v;
}

// ---------------- launch ----------------

extern "C" void kernel_launch(void* const* d_in, const int* in_sizes, int n_in,
                              void* d_out, int out_size, void* d_ws, size_t ws_size,
                              hipStream_t stream)
{
  (void)in_sizes; (void)n_in; (void)out_size; (void)ws_size;
  const int*   word  = (const int*)d_in[0];
  const int*   label = (const int*)d_in[1];
  const float* emb   = (const float*)d_in[2];
  const float* w_ih0 = (const float*)d_in[3];
  const float* w_hh0 = (const float*)d_in[4];
  const float* b_ih0 = (const float*)d_in[5];
  const float* b_hh0 = (const float*)d_in[6];
  const float* w_ih1 = (const float*)d_in[7];
  const float* w_hh1 = (const float*)d_in[8];
  const float* b_ih1 = (const float*)d_in[9];
  const float* b_hh1 = (const float*)d_in[10];
  const float* w_out = (const float*)d_in[11];
  const float* b_out = (const float*)d_in[12];
  const float* start_t = (const float*)d_in[13];
  const float* end_t   = (const float*)d_in[14];
  const float* trans   = (const float*)d_in[15];

  char* ws = (char*)d_ws;
  unsigned short* xp    = (unsigned short*)(ws + 0);            // 67108864 B
  unsigned short* xe    = (unsigned short*)(ws + 67108864);     // 20971520 B
  unsigned short* x1    = (unsigned short*)(ws + 88080384);     // 16777216 B
  unsigned short* x2    = (unsigned short*)(ws + 104857600);    // 16777216 B
  unsigned short* Bp0   = (unsigned short*)(ws + 121634816);    // 655360 B
  unsigned short* Bp1   = (unsigned short*)(ws + 122290176);    // 524288 B
  float*          bias0 = (float*)(ws + 122814464);             // 4096 B
  float*          bias1 = (float*)(ws + 122818560);             // 4096 B
  float*          em    = (float*)(ws + 122822656);             // 1179648 B
  float*          G1    = (float*)(ws + 124002304);             // 1327104 B
  float*          G2    = (float*)(ws + 125329408);             // 165888 B
  float*          G3    = (float*)(ws + 125495296);             // 20736 B
  float*          numv  = (float*)(ws + 125516032);             // 256 B

  hipLaunchKernelGGL(k_prep, dim3(2312), dim3(256), 0, stream,
                     b_ih0, b_hh0, b_ih1, b_hh1, w_ih0, w_ih1, bias0, bias1, Bp0, Bp1);
  hipLaunchKernelGGL(k_embed, dim3(32768), dim3(320), 0, stream, word, emb, xe);
  hipLaunchKernelGGL(k_gemm, dim3(256, 8), dim3(256), 0, stream, xe, Bp0, bias0, xp, 320, 10);
  hipLaunchKernelGGL(k_scan, dim3(32), dim3(256), 0, stream, w_hh0, xp, x1);
  hipLaunchKernelGGL(k_gemm, dim3(256, 8), dim3(256), 0, stream, x1, Bp1, bias1, xp, 256, 8);
  hipLaunchKernelGGL(k_scan, dim3(32), dim3(256), 0, stream, w_hh1, xp, x2);
  hipLaunchKernelGGL(k_em, dim3(256), dim3(256), 0, stream, x2, w_out, b_out, em);
  hipLaunchKernelGGL(k_crf_r1f, dim3(4096), dim3(128), 0, stream, word, em, start_t, trans, G1);
  hipLaunchKernelGGL(k_crf_reduce, dim3(512), dim3(128), 0, stream, G1, G2, 64);
  hipLaunchKernelGGL(k_crf_reduce, dim3(64), dim3(128), 0, stream, G2, G3, 8);
  hipLaunchKernelGGL(k_crf_num, dim3(64), dim3(256), 0, stream, word, label, em, start_t, end_t, trans, numv);
  hipLaunchKernelGGL(k_final, dim3(1), dim3(64), 0, stream, numv, G3, end_t, (float*)d_out);
}

// Round 3
// 823.914 us; speedup vs baseline: 1.4416x; 1.4416x over previous
//
#include <hip/hip_runtime.h>

#define TT 512
#define NB 64
#define HH 128
#define G4 512
#define HDIM 256

typedef __bf16 bf16x8 __attribute__((ext_vector_type(8)));
typedef float f32x4 __attribute__((ext_vector_type(4)));
typedef unsigned int u32x4 __attribute__((ext_vector_type(4)));
typedef unsigned int u32x2 __attribute__((ext_vector_type(2)));

union FragU { u32x4 u4; bf16x8 bf; unsigned short us[8]; };
union XPU { u32x2 v; unsigned short us[4]; };

#define SC_SIG  -1.442695041f   // fold: sigma(x) = rcp(1 + exp2(-log2e * x))
#define SC_TANH -2.885390082f   // fold: tanh(x)  = 2*rcp(1 + exp2(-2log2e * x)) - 1

__device__ __forceinline__ unsigned short f2bf(float f){
  unsigned u = __builtin_bit_cast(unsigned, f);
  return (unsigned short)((u + 0x7FFFu + ((u>>16)&1u)) >> 16);
}
__device__ __forceinline__ float bf2f(unsigned short h){
  unsigned u = ((unsigned)h) << 16;
  return __builtin_bit_cast(float, u);
}
// y is pre-scaled by SC_SIG (or SC_TANH): returns sigma
__device__ __forceinline__ float rsig(float y){
  return __builtin_amdgcn_rcpf(1.0f + __builtin_amdgcn_exp2f(y));
}
// single-instruction RNE f32->bf16 (low 16 of packed cvt)
__device__ __forceinline__ unsigned short f2bf_hw(float f){
  unsigned p;
  asm("v_cvt_pk_bf16_f32 %0, %1, %2" : "=v"(p) : "v"(f), "v"(f));
  return (unsigned short)p;
}

// ---------------- merged prep: biases + both Bp weight repacks ----------------

__global__ __launch_bounds__(256) void k_prep(
    const float* __restrict__ bi0, const float* __restrict__ bh0,
    const float* __restrict__ bi1, const float* __restrict__ bh1,
    const float* __restrict__ w_ih0, const float* __restrict__ w_ih1,
    float* __restrict__ bias0, float* __restrict__ bias1,
    unsigned short* __restrict__ Bp0, unsigned short* __restrict__ Bp1)
{
  int id = blockIdx.x*256 + threadIdx.x;
  if (id < 2048){
    int n = id & 511;
    float s = ((n >> 7) == 2) ? SC_TANH : SC_SIG;
    if (id < 1024) bias0[id] = (bi0[id] + bh0[id]) * s;
    else { int k = id - 1024; bias1[k] = (bi1[k] + bh1[k]) * s; }
    return;
  }
  id -= 2048;
  if (id < 320*1024){
    int k = id >> 10, c = id & 1023;
    int dir = c >> 9, n = c & 511;
    float s = ((n >> 7) == 2) ? SC_TANH : SC_SIG;
    float v = (k < 300) ? w_ih0[((size_t)(dir*512 + n))*300 + k] * s : 0.f;
    Bp0[(((size_t)(k>>3))*1024 + c)*8 + (k&7)] = f2bf(v);
    return;
  }
  id -= 320*1024;
  if (id < 256*1024){
    int k = id >> 10, c = id & 1023;
    int dir = c >> 9, n = c & 511;
    float s = ((n >> 7) == 2) ? SC_TANH : SC_SIG;
    float v = w_ih1[((size_t)(dir*512 + n))*256 + k] * s;
    Bp1[(((size_t)(k>>3))*1024 + c)*8 + (k&7)] = f2bf(v);
  }
}

// x_emb[row][c] bf16, row = t*64+b, padded to 320 cols
__global__ __launch_bounds__(320) void k_embed(
    const int* __restrict__ word, const float* __restrict__ emb,
    unsigned short* __restrict__ xe)
{
  int row = blockIdx.x;       // 0..32767
  int c = threadIdx.x;        // 0..319
  int t = row >> 6, b = row & 63;
  int wd = word[b*TT + t];
  float v = (c < 300) ? emb[(size_t)wd*300 + c] : 0.f;
  xe[(size_t)row*320 + c] = f2bf(v);
}

// ---------------- input GEMM: xp = A(32768 x K) * Bp(K x 1024) + bias ----------------
// output layout: xp[t][b64][dir][u128][g4] bf16 = row*1024 + dir*512 + u*4 + g
// (row-local stride-8B scatter; matches scan's per-lane 8B gate quads)

__global__ __launch_bounds__(256) void k_gemm(
    const unsigned short* __restrict__ A,   // [32768][lda] bf16
    const unsigned short* __restrict__ Bp,  // [K/8][1024][8] bf16
    const float* __restrict__ bias,         // [1024]
    unsigned short* __restrict__ xp,
    const int lda, const int KB)
{
  const int tid = threadIdx.x;
  const int l = tid & 63, w = tid >> 6;
  const int quad = l >> 4, lo = l & 15;
  const int wm = w >> 1, wn = w & 1;
  const int M0 = blockIdx.x * 128;
  const int N0 = blockIdx.y * 128;

  __shared__ __align__(16) unsigned short Asl[4*128*8];  // [q][m][8]
  __shared__ __align__(16) unsigned short Bsl[4*128*8];  // [q][n][8]

  f32x4 acc[4][4] = {};

  for (int kb=0; kb<KB; ++kb){
    const int k0 = kb*32;
    u32x4 va[2], vb[2];
    #pragma unroll
    for (int hh=0; hh<2; ++hh){
      const int cch = tid + hh*256;
      const int q = cch >> 7, mm = cch & 127;
      va[hh] = *(const u32x4*)(A + (size_t)(M0+mm)*lda + k0 + q*8);
      vb[hh] = *(const u32x4*)(Bp + (((size_t)((k0>>3)+q))*1024 + N0 + mm)*8);
    }
    __syncthreads();   // WAR vs previous iteration's frag reads
    #pragma unroll
    for (int hh=0; hh<2; ++hh){
      const int cch = tid + hh*256;
      *(u32x4*)&Asl[cch*8] = va[hh];
      *(u32x4*)&Bsl[cch*8] = vb[hh];
    }
    __syncthreads();

    FragU af[4], bfg[4];
    #pragma unroll
    for (int mt=0; mt<4; ++mt)
      af[mt].u4 = *(const u32x4*)&Asl[((quad<<7) + wm*64 + mt*16 + lo)*8];
    #pragma unroll
    for (int nt=0; nt<4; ++nt)
      bfg[nt].u4 = *(const u32x4*)&Bsl[((quad<<7) + wn*64 + nt*16 + lo)*8];
    #pragma unroll
    for (int mt=0; mt<4; ++mt)
      #pragma unroll
      for (int nt=0; nt<4; ++nt)
        acc[mt][nt] = __builtin_amdgcn_mfma_f32_16x16x32_bf16(af[mt].bf, bfg[nt].bf, acc[mt][nt], 0, 0, 0);
  }

  #pragma unroll
  for (int mt=0; mt<4; ++mt){
    #pragma unroll
    for (int nt=0; nt<4; ++nt){
      const int col = N0 + wn*64 + nt*16 + lo;
      const int dir = col >> 9, n = col & 511;
      const int g = n >> 7, u = n & 127;
      const float bv = bias[col];
      #pragma unroll
      for (int r=0; r<4; ++r){
        const int row = M0 + wm*64 + mt*16 + quad*4 + r;
        const size_t o = (size_t)row*1024 + dir*512 + u*4 + g;
        xp[o] = f2bf(acc[mt][nt][r] + bv);
      }
    }
  }
}

// ---------------- BiLSTM scan ----------------
// 64 WGs x 4 waves (1 wave/SIMD on 64 CUs): bid = dir*32 + bg; 2 seqs/WG.
// Per-step budget (R0 counters, scaled to active CUs): MFMA issue ~500cy
// (32 x ~15.7cy/SIMD), epilogue VALU ~430cy SERIAL after the last MFMA,
// sync/LDS ~210cy -> 1143cy. This round: hide the epilogue inside the
// MFMA issue shadow by staging kq3 per-gate: after i/g/f tiles' last
// accumulate, compute si/tg/sf/c/tanh(c) while the o-tiles still issue.
// Tail after the last MFMA = o-select -> exp2 -> rcp -> mul -> cvt ->
// ds_write (~80cy instead of ~300+).
// Replicated-A, BATCH-MAJOR: A[m][k] = h[m>>3][k]; lane reads acc[nt][0]
// only (row quad*4 -> batch quad>>1). xp bf16->f32 unpack (xuf) moved into
// the ds_read-wait shadow. Single-instruction v_cvt_pk_bf16_f32 for h.
// Per-step prefetch ring + per-step store (R0's best; R1 ob-batching lost).

__global__ __launch_bounds__(256, 1) void k_scan(
    const float* __restrict__ w_hh,          // [2][512][128]
    const unsigned short* __restrict__ xp,   // [t][64][2][128][4] bf16
    unsigned short* __restrict__ xout)       // [t][64][256] bf16
{
  const int bid = blockIdx.x;           // 0..63
  const int dir = bid >> 5, bg = bid & 31;
  const int tid = threadIdx.x;          // 0..255
  const int l = tid & 63, w = tid >> 6;
  const int quad = l >> 4, lo = l & 15;
  const int qb = quad >> 1;             // owned batch (0/1), batch-major
  const int qh = quad & 1;              // owned unit-half (0/1)
  const int uu = w*32 + qh*16 + lo;     // owned unit [0,128)
  const int bglob = bg*2 + qb;          // owned global batch

  // static weights as B-frags: tile nt: gate g=nt>>1, units w*32+(nt&1)*16+lo
  // gate order: 0=i, 1=f, 2=g(tanh), 3=o
  FragU bw[8][4];
  {
    const float* wb = w_hh + (size_t)dir*G4*HH;
    #pragma unroll
    for (int nt=0; nt<8; ++nt){
      const int g = nt >> 1;
      const float s = (g == 2) ? SC_TANH : SC_SIG;
      const int grow = g*HH + w*32 + (nt&1)*16 + lo;
      #pragma unroll
      for (int kq=0; kq<4; ++kq){
        const float* p = wb + (size_t)grow*HH + kq*32 + quad*8;
        #pragma unroll
        for (int j=0; j<8; ++j) bw[nt][kq].us[j] = f2bf(p[j] * s);
      }
    }
  }

  __shared__ __align__(16) unsigned short hbuf[2][2][160];  // [buf][batch][k]
  for (int i = tid; i < 2*2*160; i += 256) ((unsigned short*)hbuf)[i] = 0;
  __syncthreads();

  float c = 0.f;
  const int t0 = dir ? (TT-1) : 0;
  const int dt = dir ? -1 : 1;
  const unsigned short* xpb = xp + (size_t)bglob*1024 + dir*512 + uu*4;
  unsigned short* xob = xout + (size_t)bglob*HDIM + dir*HH + uu;

  // depth-4 register prefetch of xp (8 B/lane, dwordx2); step stride 65536
  u32x2 pf[4];
  #pragma unroll
  for (int k=0; k<4; ++k)
    pf[k] = *(const u32x2*)(xpb + (size_t)(t0 + dt*k)*65536);

  const f32x4 zero4 = {0.f, 0.f, 0.f, 0.f};

  for (int ob=0; ob<TT/4; ++ob){
    #pragma unroll
    for (int ph=0; ph<4; ++ph){
      const int it = ob*4 + ph;
      const int t = t0 + dt*it;
      const int rb = ph & 1;          // read h buffer (starts at 0)
      const int wb2 = rb ^ 1;         // write h buffer

      // A-frags: A[m=lo][k=kq*32+quad*8+j] = h[lo>>3][k]  (broadcast reads)
      FragU af[4];
      #pragma unroll
      for (int kq=0; kq<4; ++kq)
        af[kq].u4 = *(const u32x4*)&hbuf[rb][lo >> 3][kq*32 + quad*8];

      // unpack this step's xp in the LDS-wait shadow
      XPU xu; xu.v = pf[ph];
      const float xuf0 = bf2f(xu.us[0]);
      const float xuf1 = bf2f(xu.us[1]);
      const float xuf2 = bf2f(xu.us[2]);
      const float xuf3 = bf2f(xu.us[3]);
      // reload ring slot for step it+4 (addr calc + issue in MFMA shadow)
      {
        const int itp = (it+4 < TT) ? (it+4) : (TT-1);
        pf[ph] = *(const u32x2*)(xpb + (size_t)(t0 + dt*itp)*65536);
      }

      // kq 0..2: all 8 tiles, fully pipelined
      f32x4 acc[8];
      #pragma unroll
      for (int nt=0; nt<8; ++nt)
        acc[nt] = __builtin_amdgcn_mfma_f32_16x16x32_bf16(af[0].bf, bw[nt][0].bf, zero4, 0, 0, 0);
      #pragma unroll
      for (int kq=1; kq<3; ++kq)
        #pragma unroll
        for (int nt=0; nt<8; ++nt)
          acc[nt] = __builtin_amdgcn_mfma_f32_16x16x32_bf16(af[kq].bf, bw[nt][kq].bf, acc[nt], 0, 0, 0);

      // kq3 staged by gate: i, g, f issue first; their epilogue VALU
      // overlaps the remaining MFMA issue. o-tiles last -> short tail.
      acc[0] = __builtin_amdgcn_mfma_f32_16x16x32_bf16(af[3].bf, bw[0][3].bf, acc[0], 0, 0, 0);
      acc[1] = __builtin_amdgcn_mfma_f32_16x16x32_bf16(af[3].bf, bw[1][3].bf, acc[1], 0, 0, 0);
      acc[4] = __builtin_amdgcn_mfma_f32_16x16x32_bf16(af[3].bf, bw[4][3].bf, acc[4], 0, 0, 0);
      acc[5] = __builtin_amdgcn_mfma_f32_16x16x32_bf16(af[3].bf, bw[5][3].bf, acc[5], 0, 0, 0);
      const float si = rsig((qh ? acc[1][0] : acc[0][0]) + xuf0);
      const float tg = __builtin_fmaf(2.0f, rsig((qh ? acc[5][0] : acc[4][0]) + xuf2), -1.0f);
      acc[2] = __builtin_amdgcn_mfma_f32_16x16x32_bf16(af[3].bf, bw[2][3].bf, acc[2], 0, 0, 0);
      acc[3] = __builtin_amdgcn_mfma_f32_16x16x32_bf16(af[3].bf, bw[3][3].bf, acc[3], 0, 0, 0);
      const float sf = rsig((qh ? acc[3][0] : acc[2][0]) + xuf1);
      c = __builtin_fmaf(sf, c, si*tg);
      const float tb = __builtin_fmaf(2.0f, rsig(SC_TANH*c), -1.0f);
      acc[6] = __builtin_amdgcn_mfma_f32_16x16x32_bf16(af[3].bf, bw[6][3].bf, acc[6], 0, 0, 0);
      acc[7] = __builtin_amdgcn_mfma_f32_16x16x32_bf16(af[3].bf, bw[7][3].bf, acc[7], 0, 0, 0);
      const float so = rsig((qh ? acc[7][0] : acc[6][0]) + xuf3);

      const float h = so * tb;
      const unsigned short hb = f2bf_hw(h);
      hbuf[wb2][qb][uu] = hb;
      xob[(size_t)t*NB*HDIM] = hb;

      // raw barrier: wait LDS only — vmem (prefetch/stores) stays in flight
      asm volatile("s_waitcnt lgkmcnt(0)\n\ts_barrier" ::: "memory");
    }
  }
}

// ---------------- emission GEMM: em[b][t][l] = x2 row . w_out[l] + b_out[l] ----------------

__global__ __launch_bounds__(256) void k_em(
    const unsigned short* __restrict__ x2,  // [32768][256] bf16
    const float* __restrict__ w_out,        // [9][256]
    const float* __restrict__ b_out,        // [9]
    float* __restrict__ em)                 // [64][512][9]
{
  const int tid = threadIdx.x;
  const int l = tid & 63, w = tid >> 6;
  const int quad = l >> 4, lo = l & 15;
  const int M0 = blockIdx.x*128 + w*32;

  FragU bf[8];
  #pragma unroll
  for (int kq=0; kq<8; ++kq){
    #pragma unroll
    for (int j=0; j<8; ++j){
      float v = (lo < 9) ? w_out[lo*HDIM + kq*32 + quad*8 + j] : 0.f;
      bf[kq].us[j] = f2bf(v);
    }
  }

  f32x4 acc[2] = {};
  #pragma unroll
  for (int kq=0; kq<8; ++kq){
    FragU a0, a1;
    a0.u4 = *(const u32x4*)(x2 + ((size_t)(M0 + lo))*HDIM + kq*32 + quad*8);
    a1.u4 = *(const u32x4*)(x2 + ((size_t)(M0 + 16 + lo))*HDIM + kq*32 + quad*8);
    acc[0] = __builtin_amdgcn_mfma_f32_16x16x32_bf16(a0.bf, bf[kq].bf, acc[0], 0, 0, 0);
    acc[1] = __builtin_amdgcn_mfma_f32_16x16x32_bf16(a1.bf, bf[kq].bf, acc[1], 0, 0, 0);
  }

  if (lo < 9){
    const float bo = b_out[lo];
    #pragma unroll
    for (int mt=0; mt<2; ++mt){
      #pragma unroll
      for (int r=0; r<4; ++r){
        const int row = M0 + mt*16 + quad*4 + r;
        const int t = row >> 6, b = row & 63;
        em[((size_t)b*TT + t)*9 + lo] = acc[mt][r] + bo;
      }
    }
  }
}

// ---------------- CRF: fused build + radix-8 LSE-matmul reduction ----------------

__global__ __launch_bounds__(128) void k_crf_r1f(
    const int* __restrict__ word, const float* __restrict__ em,
    const float* __restrict__ start_t, const float* __restrict__ trans,
    float* __restrict__ dst)                // [64][64][81]
{
  const int bid = blockIdx.x;       // 64*64
  const int b = bid >> 6, g = bid & 63;
  const int tid = threadIdx.x;
  const int t0 = g*8;
  __shared__ float R[2][81];
  __shared__ float emsh[8][9];
  __shared__ int wsh[8];
  if (tid < 72){
    int s = tid/9, j = tid - (tid/9)*9;
    emsh[s][j] = em[((size_t)b*TT + t0+s)*9 + j];
  }
  if (tid < 8) wsh[tid] = word[b*TT + t0 + tid];
  __syncthreads();
  int i=0, j=0; float tr[9];
  if (tid < 81){
    i = tid/9; j = tid - i*9;
    #pragma unroll
    for (int k=0;k<9;++k) tr[k] = trans[k*9+j];   // trans[i][j] = tr[i]
    float v;
    if (t0 == 0) v = start_t[j] + emsh[0][j];
    else if (wsh[0] > 0) v = tr[i] + emsh[0][j];
    else v = (i==j) ? 0.f : -1e30f;
    R[0][tid] = v;
  }
  int cur = 0;
  for (int s=1; s<8; ++s){
    __syncthreads();
    if (tid < 81){
      if (wsh[s] > 0){
        float a[9], mx = -3.0e38f;
        #pragma unroll
        for (int k=0;k<9;++k){ a[k] = R[cur][i*9+k] + tr[k]; mx = fmaxf(mx, a[k]); }
        float sm = 0.f;
        #pragma unroll
        for (int k=0;k<9;++k) sm += __expf(a[k]-mx);
        R[cur^1][tid] = mx + __logf(sm) + emsh[s][j];
      } else {
        R[cur^1][tid] = R[cur][tid];
      }
    }
    cur ^= 1;
  }
  __syncthreads();
  if (tid < 81) dst[((size_t)bid)*81 + tid] = R[cur][tid];
}

// dst = radix-8 LSE-matmul reduction of src groups (order-preserving)
__global__ __launch_bounds__(128) void k_crf_reduce(
    const float* __restrict__ src, float* __restrict__ dst, const int nm)
{
  const int bid = blockIdx.x;
  const int ng = nm >> 3;
  const int b = bid / ng, g = bid - b*ng;
  const int tid = threadIdx.x;
  __shared__ float R[2][81];
  const float* base = src + ((size_t)b*nm + g*8)*81;
  if (tid < 81) R[0][tid] = base[tid];
  int cur = 0;
  for (int s=1; s<8; ++s){
    __syncthreads();
    if (tid < 81){
      int i = tid/9, j = tid - (tid/9)*9;
      const float* M = base + (size_t)s*81;
      float a[9], mx = -3.0e38f;
      #pragma unroll
      for (int k=0;k<9;++k){ a[k] = R[cur][i*9+k] + M[k*9+j]; mx = fmaxf(mx, a[k]); }
      float sm = 0.f;
      #pragma unroll
      for (int k=0;k<9;++k) sm += __expf(a[k]-mx);
      R[cur^1][tid] = mx + __logf(sm);
    }
    cur ^= 1;
  }
  __syncthreads();
  if (tid < 81) dst[((size_t)b*ng + g)*81 + tid] = R[cur][tid];
}

__global__ __launch_bounds__(256) void k_crf_num(
    const int* __restrict__ word, const int* __restrict__ label,
    const float* __restrict__ em, const float* __restrict__ start_t,
    const float* __restrict__ end_t, const float* __restrict__ trans,
    float* __restrict__ numv)
{
  const int b = blockIdx.x, tid = threadIdx.x;
  __shared__ float sred[256];
  __shared__ int ssend;
  int ms = 0;
  for (int t=tid; t<TT; t+=256) ms += (word[b*TT+t] > 0) ? 1 : 0;
  sred[tid] = (float)ms;
  __syncthreads();
  for (int st=128; st>0; st>>=1){ if (tid<st) sred[tid] += sred[tid+st]; __syncthreads(); }
  if (tid==0) ssend = (int)sred[0] - 1;
  __syncthreads();
  const int send = ssend;
  float part = 0.f;
  for (int t=tid; t<TT; t+=256){
    int tag = label[b*TT+t];
    float es = em[((size_t)b*TT+t)*9 + tag];
    if (t == 0) part += start_t[tag] + es;
    else if (word[b*TT+t] > 0) part += trans[label[b*TT+t-1]*9 + tag] + es;
    if (t == send) part += end_t[tag];
  }
  __syncthreads();
  sred[tid] = part;
  __syncthreads();
  for (int st=128; st>0; st>>=1){ if (tid<st) sred[tid] += sred[tid+st]; __syncthreads(); }
  if (tid==0) numv[b] = sred[0];
}

__global__ __launch_bounds__(64) void k_final(
    const float* __restrict__ numv, const float* __restrict__ G3,
    const float* __restrict__ end_t, float* __restrict__ out)
{
  const int b = threadIdx.x;  // 0..63
  float a[9], mx = -3.0e38f;
  #pragma unroll
  for (int j=0;j<9;++j){ a[j] = G3[b*81 + j] + end_t[j]; mx = fmaxf(mx, a[j]); }
  float sm = 0.f;
  #pragma unroll
  for (int j=0;j<9;++j) sm += __expf(a[j]-mx);
  float denom = mx + __logf(sm);
  float v = numv[b] - denom;
  #pragma unroll
  for (int off=32; off>0; off>>=1) v += __shfl_down(v, off, 64);
  if (b == 0) out[0] = -v;
}

// ---------------- launch ----------------

extern "C" void kernel_launch(void* const* d_in, const int* in_sizes, int n_in,
                              void* d_out, int out_size, void* d_ws, size_t ws_size,
                              hipStream_t stream)
{
  (void)in_sizes; (void)n_in; (void)out_size; (void)ws_size;
  const int*   word  = (const int*)d_in[0];
  const int*   label = (const int*)d_in[1];
  const float* emb   = (const float*)d_in[2];
  const float* w_ih0 = (const float*)d_in[3];
  const float* w_hh0 = (const float*)d_in[4];
  const float* b_ih0 = (const float*)d_in[5];
  const float* b_hh0 = (const float*)d_in[6];
  const float* w_ih1 = (const float*)d_in[7];
  const float* w_hh1 = (const float*)d_in[8];
  const float* b_ih1 = (const float*)d_in[9];
  const float* b_hh1 = (const float*)d_in[10];
  const float* w_out = (const float*)d_in[11];
  const float* b_out = (const float*)d_in[12];
  const float* start_t = (const float*)d_in[13];
  const float* end_t   = (const float*)d_in[14];
  const float* trans   = (const float*)d_in[15];

  char* ws = (char*)d_ws;
  unsigned short* xp    = (unsigned short*)(ws + 0);            // 67108864 B
  unsigned short* xe    = (unsigned short*)(ws + 67108864);     // 20971520 B
  unsigned short* x1    = (unsigned short*)(ws + 88080384);     // 16777216 B
  unsigned short* x2    = (unsigned short*)(ws + 104857600);    // 16777216 B
  unsigned short* Bp0   = (unsigned short*)(ws + 121634816);    // 655360 B
  unsigned short* Bp1   = (unsigned short*)(ws + 122290176);    // 524288 B
  float*          bias0 = (float*)(ws + 122814464);             // 4096 B
  float*          bias1 = (float*)(ws + 122818560);             // 4096 B
  float*          em    = (float*)(ws + 122822656);             // 1179648 B
  float*          G1    = (float*)(ws + 124002304);             // 1327104 B
  float*          G2    = (float*)(ws + 125329408);             // 165888 B
  float*          G3    = (float*)(ws + 125495296);             // 20736 B
  float*          numv  = (float*)(ws + 125516032);             // 256 B

  hipLaunchKernelGGL(k_prep, dim3(2312), dim3(256), 0, stream,
                     b_ih0, b_hh0, b_ih1, b_hh1, w_ih0, w_ih1, bias0, bias1, Bp0, Bp1);
  hipLaunchKernelGGL(k_embed, dim3(32768), dim3(320), 0, stream, word, emb, xe);
  hipLaunchKernelGGL(k_gemm, dim3(256, 8), dim3(256), 0, stream, xe, Bp0, bias0, xp, 320, 10);
  hipLaunchKernelGGL(k_scan, dim3(64), dim3(256), 0, stream, w_hh0, xp, x1);
  hipLaunchKernelGGL(k_gemm, dim3(256, 8), dim3(256), 0, stream, x1, Bp1, bias1, xp, 256, 8);
  hipLaunchKernelGGL(k_scan, dim3(64), dim3(256), 0, stream, w_hh1, xp, x2);
  hipLaunchKernelGGL(k_em, dim3(256), dim3(256), 0, stream, x2, w_out, b_out, em);
  hipLaunchKernelGGL(k_crf_r1f, dim3(4096), dim3(128), 0, stream, word, em, start_t, trans, G1);
  hipLaunchKernelGGL(k_crf_reduce, dim3(512), dim3(128), 0, stream, G1, G2, 64);
  hipLaunchKernelGGL(k_crf_reduce, dim3(64), dim3(128), 0, stream, G2, G3, 8);
  hipLaunchKernelGGL(k_crf_num, dim3(64), dim3(256), 0, stream, word, label, em, start_t, end_t, trans, numv);
  hipLaunchKernelGGL(k_final, dim3(1), dim3(64), 0, stream, numv, G3, end_t, (float*)d_out);
}